// Round 2
// baseline (247.278 us; speedup 1.0000x reference)
//
#include <hip/hip_runtime.h>
#include <math.h>

// ClassMamba collapses: output = [upd_cls, patch(unchanged)].
// upd_cls depends only on token 0 (causal conv + scan from h0=0); A_log dead.
// Round 2: single fused kernel. Blocks 0..31 run the 5-stage GEMV chain with
// sub-grid barriers; blocks 32..255 do the 67 MB copy concurrently.

#define B_SZ 4
#define DIM 512
#define D_INNER 1024
#define L_TOK 4097
#define TOK_STRIDE (L_TOK * DIM)   // floats per batch
#define PB4 (TOK_STRIDE / 4)       // 524416 float4 per batch
#define DT_RANK 32
#define D_STATE 16
#define NCHAIN 32
#define NBLOCK 256
#define NTHR 256

__device__ __forceinline__ float silu_f(float v) { return v / (1.f + expf(-v)); }

__device__ __forceinline__ float dot512(const float4* __restrict__ a,
                                        const float4* __restrict__ b) {
    float acc = 0.f;
#pragma unroll 8
    for (int k = 0; k < 128; ++k) {
        float4 x = a[k], y = b[k];
        acc += x.x * y.x + x.y * y.y + x.z * y.z + x.w * y.w;
    }
    return acc;
}

__device__ __forceinline__ float dot1024(const float4* __restrict__ a,
                                         const float4* __restrict__ b) {
    float acc = 0.f;
#pragma unroll 8
    for (int k = 0; k < 256; ++k) {
        float4 x = a[k], y = b[k];
        acc += x.x * y.x + x.y * y.y + x.z * y.z + x.w * y.w;
    }
    return acc;
}

// barrier among the NCHAIN chain blocks; ctr[phase] pre-zeroed by k_init
__device__ __forceinline__ void chain_barrier(unsigned* ctr, int phase) {
    __syncthreads();
    if (threadIdx.x == 0) {
        __hip_atomic_fetch_add(&ctr[phase], 1u, __ATOMIC_RELEASE,
                               __HIP_MEMORY_SCOPE_AGENT);
        while (__hip_atomic_load(&ctr[phase], __ATOMIC_ACQUIRE,
                                 __HIP_MEMORY_SCOPE_AGENT) < (unsigned)NCHAIN) {
            __builtin_amdgcn_s_sleep(8);
        }
    }
    __syncthreads();
}

__global__ void k_init(unsigned* __restrict__ ctr) {
    if (threadIdx.x < 8) ctr[threadIdx.x] = 0u;
}

__global__ void __launch_bounds__(NTHR, 1)
k_fused(const float* __restrict__ x, const float* __restrict__ q_w,
        const float* __restrict__ in_proj_w, const float* __restrict__ conv_w,
        const float* __restrict__ conv_b, const float* __restrict__ x_proj_w,
        const float* __restrict__ dt_w, const float* __restrict__ dt_b,
        const float* __restrict__ Dp, const float* __restrict__ out_proj_w,
        const float* __restrict__ proj_w, const float* __restrict__ proj_b,
        float* __restrict__ out, float* __restrict__ ws, unsigned* __restrict__ ctr) {
    const int blk = blockIdx.x;
    const int tid = threadIdx.x;

    float* q_ws  = ws;           // 2048
    float* xs_ws = ws + 2048;    // 4096
    float* sz_ws = ws + 6144;    // 4096
    float* yy_ws = ws + 10240;   // 4096
    float* o_ws  = ws + 14336;   // 2048

    if (blk >= NCHAIN) {
        // ---------------- copy path: out[:] = x[:] except the 4 cls rows ----
        const float4* x4 = (const float4*)x;
        float4* o4 = (float4*)out;
        const unsigned stride = (NBLOCK - NCHAIN) * NTHR;  // 57344
        const unsigned n4 = (unsigned)(B_SZ * PB4);        // 2097664
        for (unsigned i = (unsigned)(blk - NCHAIN) * NTHR + tid; i < n4; i += stride) {
            unsigned r = i;
            if (r >= 2u * PB4) r -= 2u * PB4;
            if (r >= (unsigned)PB4) r -= (unsigned)PB4;
            if (r >= 128u) o4[i] = x4[i];  // skip float4 idx 0..127 of each batch
        }
        return;
    }

    // ---------------- chain path: blocks 0..31, 8192 threads --------------
    const int gt = blk * NTHR + tid;  // 0..8191

    // stage 1: q[b,d] = dot(cls[b], q_w[d])    (2048 threads)
    if (gt < B_SZ * DIM) {
        int b = gt >> 9, d = gt & 511;
        const float4* cls = (const float4*)(x + (size_t)b * TOK_STRIDE);
        q_ws[b * DIM + d] = dot512((const float4*)(q_w + (size_t)d * DIM), cls);
    }
    chain_barrier(ctr, 0);

    // stage 2: xz row + conv tap/silu          (8192 threads)
    {
        int b = gt >> 11, j = gt & 2047;
        float acc = dot512((const float4*)(in_proj_w + (size_t)j * DIM),
                           (const float4*)(q_ws + b * DIM));
        if (j < D_INNER)
            xs_ws[b * D_INNER + j] = silu_f(acc * conv_w[j * 4 + 3] + conv_b[j]);
        else
            sz_ws[b * D_INNER + (j - D_INNER)] = silu_f(acc);
    }
    chain_barrier(ctr, 1);

    // stage 3: x_dbl (redundant per block) + delta + scan@t0 + gate
    // blocks 0..15: block bb -> b = bb>>2, d = (bb&3)*256 + tid
    if (blk < 16) {
        __shared__ float part[64][5];
        __shared__ float xds[64];
        int b = blk >> 2;
        const float* xsb = xs_ws + b * D_INNER;
        int r = tid >> 2, p = tid & 3;
        {
            const float4* w = (const float4*)(x_proj_w + r * D_INNER + p * 256);
            const float4* v = (const float4*)(xsb + p * 256);
            float acc = 0.f;
#pragma unroll 8
            for (int k = 0; k < 64; ++k) {
                float4 wv = w[k], cv = v[k];
                acc += wv.x * cv.x + wv.y * cv.y + wv.z * cv.z + wv.w * cv.w;
            }
            part[r][p] = acc;
        }
        __syncthreads();
        if (tid < 64) xds[tid] = part[tid][0] + part[tid][1] + part[tid][2] + part[tid][3];
        __syncthreads();

        float S = 0.f;
#pragma unroll
        for (int n = 0; n < D_STATE; ++n) S += xds[32 + n] * xds[48 + n];
        int d = (blk & 3) * 256 + tid;
        float dp = dt_b[d];
        const float4* dw = (const float4*)(dt_w + d * DT_RANK);
#pragma unroll
        for (int rr = 0; rr < 8; ++rr) {
            float4 wv = dw[rr];
            dp += xds[rr * 4] * wv.x + xds[rr * 4 + 1] * wv.y +
                  xds[rr * 4 + 2] * wv.z + xds[rr * 4 + 3] * wv.w;
        }
        float delta = (dp > 20.f) ? dp : log1pf(expf(dp));
        float u = xsb[d];
        yy_ws[b * D_INNER + d] = u * (delta * S + Dp[d]) * sz_ws[b * D_INNER + d];
    }
    chain_barrier(ctr, 2);

    // stage 4: o[b,i] = dot(yy[b], out_proj_w[i])   (2048 threads)
    if (gt < B_SZ * DIM) {
        int b = gt >> 9, i = gt & 511;
        o_ws[b * DIM + i] = dot1024((const float4*)(out_proj_w + (size_t)i * D_INNER),
                                    (const float4*)(yy_ws + b * D_INNER));
    }
    chain_barrier(ctr, 3);

    // stage 5: upd[b,j] -> out token 0              (2048 threads)
    if (gt < B_SZ * DIM) {
        int b = gt >> 9, j = gt & 511;
        float acc = proj_b[j] + dot512((const float4*)(proj_w + (size_t)j * DIM),
                                       (const float4*)(o_ws + b * DIM));
        out[(size_t)b * TOK_STRIDE + j] = acc;
    }
}

extern "C" void kernel_launch(void* const* d_in, const int* in_sizes, int n_in,
                              void* d_out, int out_size, void* d_ws, size_t ws_size,
                              hipStream_t stream) {
    const float* x          = (const float*)d_in[0];
    const float* q_w        = (const float*)d_in[1];
    const float* in_proj_w  = (const float*)d_in[2];
    const float* conv_w     = (const float*)d_in[3];
    const float* conv_b     = (const float*)d_in[4];
    const float* x_proj_w   = (const float*)d_in[5];
    const float* dt_w       = (const float*)d_in[6];
    const float* dt_b       = (const float*)d_in[7];
    // d_in[8] = A_log: unused (h0 = 0)
    const float* Dp         = (const float*)d_in[9];
    const float* out_proj_w = (const float*)d_in[10];
    const float* proj_w     = (const float*)d_in[11];
    const float* proj_b     = (const float*)d_in[12];
    float* out = (float*)d_out;
    float* ws  = (float*)d_ws;
    unsigned* ctr = (unsigned*)(ws + 18432);

    k_init<<<1, 64, 0, stream>>>(ctr);
    k_fused<<<NBLOCK, NTHR, 0, stream>>>(x, q_w, in_proj_w, conv_w, conv_b,
                                         x_proj_w, dt_w, dt_b, Dp, out_proj_w,
                                         proj_w, proj_b, out, ws, ctr);
}